// Round 2
// baseline (332.731 us; speedup 1.0000x reference)
//
#include <hip/hip_runtime.h>
#include <cstdint>
#include <cstddef>

typedef unsigned short u16;
typedef unsigned int u32;
typedef __attribute__((ext_vector_type(2))) float f32x2;
typedef __attribute__((ext_vector_type(4))) float f32x4;
typedef __attribute__((ext_vector_type(8))) short short8;
typedef __attribute__((ext_vector_type(4))) u16 u16x4;

#define DEV static __device__ __forceinline__
#define HW 16384

DEV u16 f2bf(float f) {
  u32 u = __float_as_uint(f);
  u = (u + 0x7fffu + ((u >> 16) & 1u)) >> 16;
  return (u16)u;
}
DEV float bf2f(u16 h) { return __uint_as_float(((u32)h) << 16); }

DEV void split8(const float* p, short8& hi, short8& lo) {
  f32x4 v0 = *(const f32x4*)p;
  f32x4 v1 = *(const f32x4*)(p + 4);
  #pragma unroll
  for (int j = 0; j < 4; ++j) {
    u16 h0 = f2bf(v0[j]);
    hi[j] = (short)h0; lo[j] = (short)f2bf(v0[j] - bf2f(h0));
    u16 h1 = f2bf(v1[j]);
    hi[4 + j] = (short)h1; lo[4 + j] = (short)f2bf(v1[j] - bf2f(h1));
  }
}
DEV void mfma3(f32x4& acc, short8 ah, short8 al, short8 bh, short8 bl) {
  acc = __builtin_amdgcn_mfma_f32_16x16x32_bf16(ah, bh, acc, 0, 0, 0);
  acc = __builtin_amdgcn_mfma_f32_16x16x32_bf16(ah, bl, acc, 0, 0, 0);
  acc = __builtin_amdgcn_mfma_f32_16x16x32_bf16(al, bh, acc, 0, 0, 0);
}

// ---------------------------------------------------------------------------
// Split-f32 GEMM via bf16 MFMA (3-term hi/lo):
//   C[b][m][n] = sum_k A[(ab?b:0)][m][k] * B[b][k][n],  M=K=192, f32 in/out
// BM=192 (4 waves x 48 rows), BN=32, 6 K-phases of 32.
// ---------------------------------------------------------------------------
template<int ABATCH>
__global__ __launch_bounds__(256) void gemm_split(const float* __restrict__ A,
                                                  const float* __restrict__ B,
                                                  float* __restrict__ C) {
  __shared__ __align__(16) u16 Ah[192 * 40];
  __shared__ __align__(16) u16 Al[192 * 40];
  __shared__ __align__(16) u16 Bh[32 * 40];
  __shared__ __align__(16) u16 Bl[32 * 40];
  const int t = threadIdx.x, lane = t & 63, wid = t >> 6;
  const int b = blockIdx.z, n0 = blockIdx.x * 32;
  const float* Ab = ABATCH ? (A + (size_t)b * 192 * 192) : A;
  const float* Bb = B + (size_t)b * 192 * HW;
  float* Cb = C + (size_t)b * 192 * HW;
  const int g = lane >> 4, r16 = lane & 15;
  f32x4 acc[3][2] = {};
  #pragma unroll 1
  for (int p = 0; p < 6; ++p) {
    // stage A tile: 192 rows x 32 k, split hi/lo
    #pragma unroll
    for (int i = 0; i < 6; ++i) {
      int vi = t + i * 256;
      int row = vi >> 3, c4 = (vi & 7) << 2;
      f32x4 v = *(const f32x4*)&Ab[(size_t)row * 192 + p * 32 + c4];
      u16x4 h, l;
      #pragma unroll
      for (int j = 0; j < 4; ++j) {
        h[j] = f2bf(v[j]);
        l[j] = f2bf(v[j] - bf2f(h[j]));
      }
      *(u16x4*)&Ah[row * 40 + c4] = h;
      *(u16x4*)&Al[row * 40 + c4] = l;
    }
    // stage B tile: 32 k x 32 n, transposed to [n][k], split hi/lo
    {
      int kr = t >> 3, c4 = (t & 7) << 2;
      f32x4 v = *(const f32x4*)&Bb[(size_t)(p * 32 + kr) * HW + n0 + c4];
      #pragma unroll
      for (int j = 0; j < 4; ++j) {
        u16 h = f2bf(v[j]);
        u16 l = f2bf(v[j] - bf2f(h));
        Bh[(c4 + j) * 40 + kr] = h;
        Bl[(c4 + j) * 40 + kr] = l;
      }
    }
    __syncthreads();
    short8 ah[3], al[3], bh[2], bl[2];
    #pragma unroll
    for (int mf = 0; mf < 3; ++mf) {
      ah[mf] = *(const short8*)&Ah[(wid * 48 + mf * 16 + r16) * 40 + g * 8];
      al[mf] = *(const short8*)&Al[(wid * 48 + mf * 16 + r16) * 40 + g * 8];
    }
    #pragma unroll
    for (int nf = 0; nf < 2; ++nf) {
      bh[nf] = *(const short8*)&Bh[(nf * 16 + r16) * 40 + g * 8];
      bl[nf] = *(const short8*)&Bl[(nf * 16 + r16) * 40 + g * 8];
    }
    #pragma unroll
    for (int mf = 0; mf < 3; ++mf)
      #pragma unroll
      for (int nf = 0; nf < 2; ++nf)
        mfma3(acc[mf][nf], ah[mf], al[mf], bh[nf], bl[nf]);
    __syncthreads();
  }
  #pragma unroll
  for (int mf = 0; mf < 3; ++mf)
    #pragma unroll
    for (int nf = 0; nf < 2; ++nf)
      #pragma unroll
      for (int rr = 0; rr < 4; ++rr)
        Cb[(size_t)(wid * 48 + mf * 16 + g * 4 + rr) * HW + n0 + nf * 16 + r16] =
            acc[mf][nf][rr];
}

// ---------------------------------------------------------------------------
// K2: depthwise 3x3 (pad 1), f32 in/out. 8 waves, one channel each;
// tile = 8 rows x 128 cols. Optional per-channel sum-of-squares partials.
// ---------------------------------------------------------------------------
template<int SSQ>
__global__ __launch_bounds__(512) void k2_dw(const float* __restrict__ Tin,
                                             const float* __restrict__ wdw, int wco,
                                             float* __restrict__ O,
                                             float* __restrict__ ssq, int sspath) {
  const int rt = blockIdx.x, cg = blockIdx.y, b = blockIdx.z;
  const int t = threadIdx.x, lane = t & 63, w = t >> 6;
  __shared__ float In[8][10][132];
  for (int idx = t; idx < 10400; idx += 512) {
    int ch = idx / 1300, rem = idx % 1300;
    int r = rem / 130, ci = rem % 130;
    int gr = rt * 8 + r - 1, gc = ci - 1;
    float v = 0.f;
    if (gr >= 0 && gr < 128 && gc >= 0 && gc < 128)
      v = Tin[((size_t)b * 192 + cg * 8 + ch) * HW + gr * 128 + gc];
    In[ch][r][ci] = v;
  }
  float wv[9];
  #pragma unroll
  for (int j = 0; j < 9; ++j) wv[j] = wdw[(size_t)(wco + cg * 8 + w) * 9 + j];
  __syncthreads();
  float s = 0.f;
  float* Op = O + ((size_t)b * 192 + cg * 8 + w) * HW + rt * 8 * 128 + 2 * lane;
  #pragma unroll
  for (int i = 0; i < 8; ++i) {
    float a0 = 0.f, a1 = 0.f;
    #pragma unroll
    for (int dr = 0; dr < 3; ++dr) {
      f32x2 u0 = *(const f32x2*)&In[w][i + dr][2 * lane];
      f32x2 u1 = *(const f32x2*)&In[w][i + dr][2 * lane + 2];
      a0 += wv[dr * 3] * u0[0] + wv[dr * 3 + 1] * u0[1] + wv[dr * 3 + 2] * u1[0];
      a1 += wv[dr * 3] * u0[1] + wv[dr * 3 + 1] * u1[0] + wv[dr * 3 + 2] * u1[1];
    }
    f32x2 o = {a0, a1};
    *(f32x2*)&Op[(size_t)i * 128] = o;
    if (SSQ) s += a0 * a0 + a1 * a1;
  }
  if (SSQ) {
    #pragma unroll
    for (int off = 32; off; off >>= 1) s += __shfl_down(s, off);
    if (lane == 0) ssq[(((size_t)b * 2 + sspath) * 192 + cg * 8 + w) * 16 + rt] = s;
  }
}

// ---------------------------------------------------------------------------
// K3: Gram partials gp[bh][64][32][32] = Q(32,256chunk) . K^T via split MFMA.
// 4 waves/block, each owns one 256-px chunk.
// ---------------------------------------------------------------------------
__global__ __launch_bounds__(256) void k3_gram(const float* __restrict__ q,
                                               const float* __restrict__ k,
                                               float* __restrict__ gp) {
  const int ck = blockIdx.x, bh = blockIdx.y;  // 16, 24
  const int b = bh / 6, h = bh % 6;
  const int t = threadIdx.x, lane = t & 63, wid = t >> 6;
  const int r16 = lane & 15, g = lane >> 4;
  const int chunk = ck * 4 + wid;  // 0..63
  const size_t rbase = ((size_t)b * 192 + h * 32 + r16) * HW;
  const float* qp = q + rbase;
  const float* kp = k + rbase;
  f32x4 acc[2][2] = {};
  #pragma unroll 1
  for (int s = 0; s < 8; ++s) {
    int n = chunk * 256 + s * 32 + g * 8;
    short8 a0h, a0l, a1h, a1l, b0h, b0l, b1h, b1l;
    split8(&qp[n], a0h, a0l);
    split8(&qp[(size_t)16 * HW + n], a1h, a1l);
    split8(&kp[n], b0h, b0l);
    split8(&kp[(size_t)16 * HW + n], b1h, b1l);
    mfma3(acc[0][0], a0h, a0l, b0h, b0l);
    mfma3(acc[0][1], a0h, a0l, b1h, b1l);
    mfma3(acc[1][0], a1h, a1l, b0h, b0l);
    mfma3(acc[1][1], a1h, a1l, b1h, b1l);
  }
  float* outp = gp + ((size_t)bh * 64 + chunk) * 1024;
  #pragma unroll
  for (int mf = 0; mf < 2; ++mf)
    #pragma unroll
    for (int nf = 0; nf < 2; ++nf)
      #pragma unroll
      for (int rr = 0; rr < 4; ++rr)
        outp[(mf * 16 + g * 4 + rr) * 32 + nf * 16 + r16] = acc[mf][nf][rr];
}

// ---------------------------------------------------------------------------
// K4: per (b,h): reduce partials, normalize, temperature, 4x topk-softmax,
// combine with attn_w, fold W_proj -> mc[b][192][192] f32
// ---------------------------------------------------------------------------
__global__ __launch_bounds__(256) void k4_comb(const float* __restrict__ gp,
                                               const float* __restrict__ ssq,
                                               const float* __restrict__ temp,
                                               const float* __restrict__ aw,
                                               const float* __restrict__ wproj,
                                               float* __restrict__ mc) {
  const int bh = blockIdx.x, b = bh / 6, h = bh % 6;
  const int t = threadIdx.x;
  __shared__ float Gs[1024];
  __shared__ float Acm[1024];
  __shared__ float nq[32], nk[32];
  for (int e = t; e < 1024; e += 256) {
    const float* p = gp + ((size_t)bh * 64) * 1024 + e;
    float s = 0.f;
    for (int ch = 0; ch < 64; ++ch) s += p[(size_t)ch * 1024];
    Gs[e] = s;
  }
  if (t < 64) {
    int c = t & 31, pk = t >> 5;
    const float* sp = ssq + (((size_t)b * 2 + pk) * 192 + h * 32 + c) * 16;
    float s = 0.f;
    #pragma unroll
    for (int i = 0; i < 16; ++i) s += sp[i];
    float nr = fmaxf(sqrtf(s), 1e-12f);
    if (pk == 0) nq[c] = nr; else nk[c] = nr;
  }
  __syncthreads();
  const float T = temp[h];
  for (int e = t; e < 1024; e += 256) {
    int c = e >> 5, d = e & 31;
    Gs[e] = Gs[e] * T / (nq[c] * nk[d]);
  }
  __syncthreads();
  const float aw0 = aw[0], aw1 = aw[1], aw2 = aw[2], aw3 = aw[3];
  const int half = t >> 5, d = t & 31;
  for (int it = 0; it < 4; ++it) {
    const int c = it * 8 + half;
    const float v = Gs[c * 32 + d];
    int cnt = 0;
    #pragma unroll
    for (int dd = 0; dd < 32; ++dd) cnt += (Gs[c * 32 + dd] >= v) ? 1 : 0;
    float c0 = v;
    float c1 = (cnt >= 16) ? v : -3.0e38f;
    float c2 = (cnt >= 21) ? v : -3.0e38f;
    float c3 = (cnt >= 24) ? v : -3.0e38f;
    float c4 = (cnt >= 25) ? v : -3.0e38f;
    #pragma unroll
    for (int off = 16; off; off >>= 1) {
      c0 = fmaxf(c0, __shfl_xor(c0, off));
      c1 = fmaxf(c1, __shfl_xor(c1, off));
      c2 = fmaxf(c2, __shfl_xor(c2, off));
      c3 = fmaxf(c3, __shfl_xor(c3, off));
      c4 = fmaxf(c4, __shfl_xor(c4, off));
    }
    const float m = c0;
    const float ex = expf(v - m);
    float z1 = (v >= c1) ? ex : 0.f;
    float z2 = (v >= c2) ? ex : 0.f;
    float z3 = (v >= c3) ? ex : 0.f;
    float z4 = (v >= c4) ? ex : 0.f;
    #pragma unroll
    for (int off = 16; off; off >>= 1) {
      z1 += __shfl_xor(z1, off);
      z2 += __shfl_xor(z2, off);
      z3 += __shfl_xor(z3, off);
      z4 += __shfl_xor(z4, off);
    }
    float a = 0.f;
    a += (v >= c1) ? aw0 * ex / z1 : 0.f;
    a += (v >= c2) ? aw1 * ex / z2 : 0.f;
    a += (v >= c3) ? aw2 * ex / z3 : 0.f;
    a += (v >= c4) ? aw3 * ex / z4 : 0.f;
    Acm[c * 32 + d] = a;
  }
  __syncthreads();
  for (int idx = t; idx < 192 * 32; idx += 256) {
    int co = idx >> 5, dd = idx & 31;
    const float* wp = wproj + (size_t)co * 192 + h * 32;
    float s = 0.f;
    #pragma unroll
    for (int c = 0; c < 32; ++c) s += wp[c] * Acm[c * 32 + dd];
    mc[((size_t)b * 192 + co) * 192 + h * 32 + dd] = s;
  }
}

// ---------------------------------------------------------------------------
extern "C" void kernel_launch(void* const* d_in, const int* in_sizes, int n_in,
                              void* d_out, int out_size, void* d_ws, size_t ws_size,
                              hipStream_t stream) {
  const float* x     = (const float*)d_in[0];
  const float* ref   = (const float*)d_in[1];
  const float* wqkv  = (const float*)d_in[2];
  const float* wdw   = (const float*)d_in[3];
  const float* wproj = (const float*)d_in[4];
  const float* temp  = (const float*)d_in[5];
  const float* aw    = (const float*)d_in[6];
  float* out = (float*)d_out;
  char* ws = (char*)d_ws;

  const size_t S = (size_t)4 * 192 * HW * 4;  // 50331648 bytes per f32 tensor
  float* tA  = (float*)(ws);                  // conv1x1 out (q-part), later v-part
  float* tB  = (float*)(ws + S);              // conv1x1 out (k-part), later v
  float* qb  = (float*)(ws + 2 * S);
  float* kb  = (float*)(ws + 3 * S);
  float* gp  = (float*)(ws + 4 * S);                      // 6291456 B
  float* ssq = (float*)(ws + 4 * S + 6291456);            // 98304 B
  float* mc  = (float*)(ws + 4 * S + 6291456 + 98304);    // 589824 B

  // conv1x1 (split-bf16 MFMA, f32 out)
  gemm_split<0><<<dim3(512, 1, 4), 256, 0, stream>>>(wqkv, x, tA);
  gemm_split<0><<<dim3(512, 1, 4), 256, 0, stream>>>(wqkv + 192 * 192, ref, tB);
  // depthwise 3x3 (f32) + sumsq
  k2_dw<1><<<dim3(16, 24, 4), 512, 0, stream>>>(tA, wdw, 0, qb, ssq, 0);
  k2_dw<1><<<dim3(16, 24, 4), 512, 0, stream>>>(tB, wdw, 192, kb, ssq, 1);
  // Gram partials
  k3_gram<<<dim3(16, 24), 256, 0, stream>>>(qb, kb, gp);
  // v path (reuses tA, then tB)
  gemm_split<0><<<dim3(512, 1, 4), 256, 0, stream>>>(wqkv + 384 * 192, ref, tA);
  k2_dw<0><<<dim3(16, 24, 4), 512, 0, stream>>>(tA, wdw, 384, tB, nullptr, 2);
  // combine + fold proj
  k4_comb<<<dim3(24), 256, 0, stream>>>(gp, ssq, temp, aw, wproj, mc);
  // final batched GEMM (bug fix: A has per-batch stride)
  gemm_split<1><<<dim3(512, 1, 4), 256, 0, stream>>>(mc, tB, out);
}

// Round 3
// 245.311 us; speedup vs baseline: 1.3564x; 1.3564x over previous
//
#include <hip/hip_runtime.h>
#include <cstdint>
#include <cstddef>

typedef unsigned short u16;
typedef unsigned int u32;
typedef __attribute__((ext_vector_type(2))) float f32x2;
typedef __attribute__((ext_vector_type(4))) float f32x4;
typedef __attribute__((ext_vector_type(8))) short short8;
typedef __attribute__((ext_vector_type(2))) u32 u32x2;
typedef __attribute__((ext_vector_type(4))) u32 u32x4;

#define DEV static __device__ __forceinline__
#define HW 16384

DEV u16 f2bf(float f) {
  u32 u = __float_as_uint(f);
  u = (u + 0x7fffu + ((u >> 16) & 1u)) >> 16;
  return (u16)u;
}
DEV float bf2f(u16 h) { return __uint_as_float(((u32)h) << 16); }

DEV u32 packsplit(float f) {
  u16 h = f2bf(f);
  u16 l = f2bf(f - bf2f(h));
  return (u32)h | ((u32)l << 16);
}
DEV void unpack8(const u32* w, short8& hi, short8& lo) {
  #pragma unroll
  for (int i = 0; i < 8; ++i) {
    hi[i] = (short)(u16)w[i];
    lo[i] = (short)(u16)(w[i] >> 16);
  }
}
DEV void split8(const float* p, short8& hi, short8& lo) {
  f32x4 v0 = *(const f32x4*)p;
  f32x4 v1 = *(const f32x4*)(p + 4);
  #pragma unroll
  for (int j = 0; j < 4; ++j) {
    u16 h0 = f2bf(v0[j]);
    hi[j] = (short)h0; lo[j] = (short)f2bf(v0[j] - bf2f(h0));
    u16 h1 = f2bf(v1[j]);
    hi[4 + j] = (short)h1; lo[4 + j] = (short)f2bf(v1[j] - bf2f(h1));
  }
}
DEV void mfma3(f32x4& acc, short8 ah, short8 al, short8 bh, short8 bl) {
  acc = __builtin_amdgcn_mfma_f32_16x16x32_bf16(ah, bh, acc, 0, 0, 0);
  acc = __builtin_amdgcn_mfma_f32_16x16x32_bf16(ah, bl, acc, 0, 0, 0);
  acc = __builtin_amdgcn_mfma_f32_16x16x32_bf16(al, bh, acc, 0, 0, 0);
}

// ---------------------------------------------------------------------------
// ksplit: f32 -> packed split-bf16 u32 (hi | lo<<16)
// ---------------------------------------------------------------------------
__global__ __launch_bounds__(256) void ksplit(const float* __restrict__ in,
                                              u32* __restrict__ out, int n) {
  int i = blockIdx.x * 256 + threadIdx.x;
  if (i < n) out[i] = packsplit(in[i]);
}

// ---------------------------------------------------------------------------
// gemm2: C[b][m][n] = A[(ab?b:0)][m][k] * B[b][k][n], M=K=192, f32 B/C,
// A pre-split packed u32. BM=192, BN=64, 8 waves (2m x 4n), 6 K-phases.
// ---------------------------------------------------------------------------
template<int ABATCH>
__global__ __launch_bounds__(512, 4) void gemm2(const u32* __restrict__ Asp,
                                                const float* __restrict__ B,
                                                float* __restrict__ C) {
  __shared__ u32 As[192 * 34];  // 26.1 KB
  __shared__ u32 Bs[64 * 34];   // 8.7 KB
  const int t = threadIdx.x, lane = t & 63, wid = t >> 6;
  const int b = blockIdx.z, n0 = blockIdx.x * 64;
  const u32* Ab = ABATCH ? (Asp + (size_t)b * 192 * 192) : Asp;
  const float* Bb = B + (size_t)b * 192 * (size_t)HW;
  float* Cb = C + (size_t)b * 192 * (size_t)HW;
  const int wr = wid >> 2, wc = wid & 3;
  const int g = lane >> 4, r16 = lane & 15;
  const int b_n = (t & 15) * 4, b_k = t >> 4;
  f32x4 acc[6] = {};

  f32x4 Breg, Bnext;
  u32x4 Areg[3];
  Breg = *(const f32x4*)&Bb[(size_t)b_k * HW + n0 + b_n];
  #pragma unroll
  for (int i = 0; i < 3; ++i) {
    int vi = t + i * 512;
    Areg[i] = *(const u32x4*)&Ab[(size_t)(vi >> 3) * 192 + ((vi & 7) << 2)];
  }
  #pragma unroll 1
  for (int p = 0; p < 6; ++p) {
    #pragma unroll
    for (int j = 0; j < 4; ++j)
      Bs[(b_n + j) * 34 + b_k] = packsplit(Breg[j]);
    #pragma unroll
    for (int i = 0; i < 3; ++i) {
      int vi = t + i * 512;
      int row = vi >> 3, kc = (vi & 7) << 2;
      u32x2 v0 = {Areg[i][0], Areg[i][1]};
      u32x2 v1 = {Areg[i][2], Areg[i][3]};
      *(u32x2*)&As[row * 34 + kc] = v0;
      *(u32x2*)&As[row * 34 + kc + 2] = v1;
    }
    if (p < 5)
      Bnext = *(const f32x4*)&Bb[(size_t)((p + 1) * 32 + b_k) * HW + n0 + b_n];
    __syncthreads();
    if (p < 5) {
      #pragma unroll
      for (int i = 0; i < 3; ++i) {
        int vi = t + i * 512;
        Areg[i] = *(const u32x4*)&Ab[(size_t)(vi >> 3) * 192 + (p + 1) * 32 + ((vi & 7) << 2)];
      }
    }
    u32 bw[8];
    {
      const u32* bp = &Bs[(wc * 16 + r16) * 34 + g * 8];
      *(u32x2*)&bw[0] = *(const u32x2*)&bp[0];
      *(u32x2*)&bw[2] = *(const u32x2*)&bp[2];
      *(u32x2*)&bw[4] = *(const u32x2*)&bp[4];
      *(u32x2*)&bw[6] = *(const u32x2*)&bp[6];
    }
    short8 bh, bl; unpack8(bw, bh, bl);
    #pragma unroll
    for (int mf = 0; mf < 6; ++mf) {
      u32 aw[8];
      const u32* ap = &As[(wr * 96 + mf * 16 + r16) * 34 + g * 8];
      *(u32x2*)&aw[0] = *(const u32x2*)&ap[0];
      *(u32x2*)&aw[2] = *(const u32x2*)&ap[2];
      *(u32x2*)&aw[4] = *(const u32x2*)&ap[4];
      *(u32x2*)&aw[6] = *(const u32x2*)&ap[6];
      short8 ah, al; unpack8(aw, ah, al);
      acc[mf] = __builtin_amdgcn_mfma_f32_16x16x32_bf16(ah, bh, acc[mf], 0, 0, 0);
      acc[mf] = __builtin_amdgcn_mfma_f32_16x16x32_bf16(ah, bl, acc[mf], 0, 0, 0);
      acc[mf] = __builtin_amdgcn_mfma_f32_16x16x32_bf16(al, bh, acc[mf], 0, 0, 0);
    }
    __syncthreads();
    Breg = Bnext;
  }
  #pragma unroll
  for (int mf = 0; mf < 6; ++mf)
    #pragma unroll
    for (int rr = 0; rr < 4; ++rr)
      Cb[(size_t)(wr * 96 + mf * 16 + g * 4 + rr) * HW + n0 + wc * 16 + r16] =
          acc[mf][rr];
}

// ---------------------------------------------------------------------------
// K2: depthwise 3x3 (pad 1), f32 in/out. 8 waves, one channel each;
// tile = 8 rows x 128 cols. Optional per-channel sum-of-squares partials.
// ---------------------------------------------------------------------------
template<int SSQ>
__global__ __launch_bounds__(512) void k2_dw(const float* __restrict__ Tin,
                                             const float* __restrict__ wdw, int wco,
                                             float* __restrict__ O,
                                             float* __restrict__ ssq, int sspath) {
  const int rt = blockIdx.x, cg = blockIdx.y, b = blockIdx.z;
  const int t = threadIdx.x, lane = t & 63, w = t >> 6;
  __shared__ float In[8][10][132];
  for (int idx = t; idx < 10400; idx += 512) {
    int ch = idx / 1300, rem = idx % 1300;
    int r = rem / 130, ci = rem % 130;
    int gr = rt * 8 + r - 1, gc = ci - 1;
    float v = 0.f;
    if (gr >= 0 && gr < 128 && gc >= 0 && gc < 128)
      v = Tin[((size_t)b * 192 + cg * 8 + ch) * HW + gr * 128 + gc];
    In[ch][r][ci] = v;
  }
  float wv[9];
  #pragma unroll
  for (int j = 0; j < 9; ++j) wv[j] = wdw[(size_t)(wco + cg * 8 + w) * 9 + j];
  __syncthreads();
  float s = 0.f;
  float* Op = O + ((size_t)b * 192 + cg * 8 + w) * HW + rt * 8 * 128 + 2 * lane;
  #pragma unroll
  for (int i = 0; i < 8; ++i) {
    float a0 = 0.f, a1 = 0.f;
    #pragma unroll
    for (int dr = 0; dr < 3; ++dr) {
      f32x2 u0 = *(const f32x2*)&In[w][i + dr][2 * lane];
      f32x2 u1 = *(const f32x2*)&In[w][i + dr][2 * lane + 2];
      a0 += wv[dr * 3] * u0[0] + wv[dr * 3 + 1] * u0[1] + wv[dr * 3 + 2] * u1[0];
      a1 += wv[dr * 3] * u0[1] + wv[dr * 3 + 1] * u1[0] + wv[dr * 3 + 2] * u1[1];
    }
    f32x2 o = {a0, a1};
    *(f32x2*)&Op[(size_t)i * 128] = o;
    if (SSQ) s += a0 * a0 + a1 * a1;
  }
  if (SSQ) {
    #pragma unroll
    for (int off = 32; off; off >>= 1) s += __shfl_down(s, off);
    if (lane == 0) ssq[(((size_t)b * 2 + sspath) * 192 + cg * 8 + w) * 16 + rt] = s;
  }
}

// ---------------------------------------------------------------------------
// K3: Gram partials gp[bh][64][32][32] = Q(32,256chunk) . K^T via split MFMA.
// 4 waves/block, each owns one 256-px chunk.
// ---------------------------------------------------------------------------
__global__ __launch_bounds__(256) void k3_gram(const float* __restrict__ q,
                                               const float* __restrict__ k,
                                               float* __restrict__ gp) {
  const int ck = blockIdx.x, bh = blockIdx.y;  // 16, 24
  const int b = bh / 6, h = bh % 6;
  const int t = threadIdx.x, lane = t & 63, wid = t >> 6;
  const int r16 = lane & 15, g = lane >> 4;
  const int chunk = ck * 4 + wid;  // 0..63
  const size_t rbase = ((size_t)b * 192 + h * 32 + r16) * HW;
  const float* qp = q + rbase;
  const float* kp = k + rbase;
  f32x4 acc[2][2] = {};
  #pragma unroll 1
  for (int s = 0; s < 8; ++s) {
    int n = chunk * 256 + s * 32 + g * 8;
    short8 a0h, a0l, a1h, a1l, b0h, b0l, b1h, b1l;
    split8(&qp[n], a0h, a0l);
    split8(&qp[(size_t)16 * HW + n], a1h, a1l);
    split8(&kp[n], b0h, b0l);
    split8(&kp[(size_t)16 * HW + n], b1h, b1l);
    mfma3(acc[0][0], a0h, a0l, b0h, b0l);
    mfma3(acc[0][1], a0h, a0l, b1h, b1l);
    mfma3(acc[1][0], a1h, a1l, b0h, b0l);
    mfma3(acc[1][1], a1h, a1l, b1h, b1l);
  }
  float* outp = gp + ((size_t)bh * 64 + chunk) * 1024;
  #pragma unroll
  for (int mf = 0; mf < 2; ++mf)
    #pragma unroll
    for (int nf = 0; nf < 2; ++nf)
      #pragma unroll
      for (int rr = 0; rr < 4; ++rr)
        outp[(mf * 16 + g * 4 + rr) * 32 + nf * 16 + r16] = acc[mf][nf][rr];
}

// ---------------------------------------------------------------------------
// K4: per (b,h): reduce partials, normalize, temperature, 4x topk-softmax,
// combine with attn_w, fold W_proj -> mc[b][192][192] f32
// ---------------------------------------------------------------------------
__global__ __launch_bounds__(256) void k4_comb(const float* __restrict__ gp,
                                               const float* __restrict__ ssq,
                                               const float* __restrict__ temp,
                                               const float* __restrict__ aw,
                                               const float* __restrict__ wproj,
                                               float* __restrict__ mc) {
  const int bh = blockIdx.x, b = bh / 6, h = bh % 6;
  const int t = threadIdx.x;
  __shared__ float Gs[1024];
  __shared__ float Acm[1024];
  __shared__ float nq[32], nk[32];
  for (int e = t; e < 1024; e += 256) {
    const float* p = gp + ((size_t)bh * 64) * 1024 + e;
    float s = 0.f;
    for (int ch = 0; ch < 64; ++ch) s += p[(size_t)ch * 1024];
    Gs[e] = s;
  }
  if (t < 64) {
    int c = t & 31, pk = t >> 5;
    const float* sp = ssq + (((size_t)b * 2 + pk) * 192 + h * 32 + c) * 16;
    float s = 0.f;
    #pragma unroll
    for (int i = 0; i < 16; ++i) s += sp[i];
    float nr = fmaxf(sqrtf(s), 1e-12f);
    if (pk == 0) nq[c] = nr; else nk[c] = nr;
  }
  __syncthreads();
  const float T = temp[h];
  for (int e = t; e < 1024; e += 256) {
    int c = e >> 5, d = e & 31;
    Gs[e] = Gs[e] * T / (nq[c] * nk[d]);
  }
  __syncthreads();
  const float aw0 = aw[0], aw1 = aw[1], aw2 = aw[2], aw3 = aw[3];
  const int half = t >> 5, d = t & 31;
  for (int it = 0; it < 4; ++it) {
    const int c = it * 8 + half;
    const float v = Gs[c * 32 + d];
    int cnt = 0;
    #pragma unroll
    for (int dd = 0; dd < 32; ++dd) cnt += (Gs[c * 32 + dd] >= v) ? 1 : 0;
    float c0 = v;
    float c1 = (cnt >= 16) ? v : -3.0e38f;
    float c2 = (cnt >= 21) ? v : -3.0e38f;
    float c3 = (cnt >= 24) ? v : -3.0e38f;
    float c4 = (cnt >= 25) ? v : -3.0e38f;
    #pragma unroll
    for (int off = 16; off; off >>= 1) {
      c0 = fmaxf(c0, __shfl_xor(c0, off));
      c1 = fmaxf(c1, __shfl_xor(c1, off));
      c2 = fmaxf(c2, __shfl_xor(c2, off));
      c3 = fmaxf(c3, __shfl_xor(c3, off));
      c4 = fmaxf(c4, __shfl_xor(c4, off));
    }
    const float m = c0;
    const float ex = expf(v - m);
    float z1 = (v >= c1) ? ex : 0.f;
    float z2 = (v >= c2) ? ex : 0.f;
    float z3 = (v >= c3) ? ex : 0.f;
    float z4 = (v >= c4) ? ex : 0.f;
    #pragma unroll
    for (int off = 16; off; off >>= 1) {
      z1 += __shfl_xor(z1, off);
      z2 += __shfl_xor(z2, off);
      z3 += __shfl_xor(z3, off);
      z4 += __shfl_xor(z4, off);
    }
    float a = 0.f;
    a += (v >= c1) ? aw0 * ex / z1 : 0.f;
    a += (v >= c2) ? aw1 * ex / z2 : 0.f;
    a += (v >= c3) ? aw2 * ex / z3 : 0.f;
    a += (v >= c4) ? aw3 * ex / z4 : 0.f;
    Acm[c * 32 + d] = a;
  }
  __syncthreads();
  for (int idx = t; idx < 192 * 32; idx += 256) {
    int co = idx >> 5, dd = idx & 31;
    const float* wp = wproj + (size_t)co * 192 + h * 32;
    float s = 0.f;
    #pragma unroll
    for (int c = 0; c < 32; ++c) s += wp[c] * Acm[c * 32 + dd];
    mc[((size_t)b * 192 + co) * 192 + h * 32 + dd] = s;
  }
}

// ---------------------------------------------------------------------------
extern "C" void kernel_launch(void* const* d_in, const int* in_sizes, int n_in,
                              void* d_out, int out_size, void* d_ws, size_t ws_size,
                              hipStream_t stream) {
  const float* x     = (const float*)d_in[0];
  const float* ref   = (const float*)d_in[1];
  const float* wqkv  = (const float*)d_in[2];
  const float* wdw   = (const float*)d_in[3];
  const float* wproj = (const float*)d_in[4];
  const float* temp  = (const float*)d_in[5];
  const float* aw    = (const float*)d_in[6];
  float* out = (float*)d_out;
  char* ws = (char*)d_ws;

  const size_t S = (size_t)4 * 192 * HW * 4;  // 50331648 bytes per f32 tensor
  float* tA  = (float*)(ws);
  float* tB  = (float*)(ws + S);
  float* qb  = (float*)(ws + 2 * S);
  float* kb  = (float*)(ws + 3 * S);
  float* gp  = (float*)(ws + 4 * S);                        // 6291456 B
  float* ssq = (float*)(ws + 4 * S + 6291456);              // 98304 B
  float* mc  = (float*)(ws + 4 * S + 6291456 + 98304);      // 589824 B
  u32*   wsp = (u32*)(ws + 4 * S + 6291456 + 98304 + 589824);          // 442368 B
  u32*   mcp = (u32*)(ws + 4 * S + 6291456 + 98304 + 589824 + 442368); // 589824 B

  // pre-split w_qkv (576x192)
  ksplit<<<dim3(432), 256, 0, stream>>>(wqkv, wsp, 576 * 192);
  // conv1x1 q and k
  gemm2<0><<<dim3(256, 1, 4), 512, 0, stream>>>(wsp, x, tA);
  gemm2<0><<<dim3(256, 1, 4), 512, 0, stream>>>(wsp + 192 * 192, ref, tB);
  // depthwise 3x3 + sumsq
  k2_dw<1><<<dim3(16, 24, 4), 512, 0, stream>>>(tA, wdw, 0, qb, ssq, 0);
  k2_dw<1><<<dim3(16, 24, 4), 512, 0, stream>>>(tB, wdw, 192, kb, ssq, 1);
  // Gram partials
  k3_gram<<<dim3(16, 24), 256, 0, stream>>>(qb, kb, gp);
  // v path (reuse tA then tB)
  gemm2<0><<<dim3(256, 1, 4), 512, 0, stream>>>(wsp + 384 * 192, ref, tA);
  k2_dw<0><<<dim3(16, 24, 4), 512, 0, stream>>>(tA, wdw, 384, tB, nullptr, 2);
  // combine + fold proj, then pre-split mc
  k4_comb<<<dim3(24), 256, 0, stream>>>(gp, ssq, temp, aw, wproj, mc);
  ksplit<<<dim3(576), 256, 0, stream>>>(mc, mcp, 4 * 192 * 192);
  // final batched GEMM
  gemm2<1><<<dim3(256, 1, 4), 512, 0, stream>>>(mcp, tB, out);
}

// Round 4
// 240.858 us; speedup vs baseline: 1.3814x; 1.0185x over previous
//
#include <hip/hip_runtime.h>
#include <cstdint>
#include <cstddef>

typedef unsigned short u16;
typedef unsigned int u32;
typedef __attribute__((ext_vector_type(2))) float f32x2;
typedef __attribute__((ext_vector_type(4))) float f32x4;
typedef __attribute__((ext_vector_type(8))) short short8;
typedef __attribute__((ext_vector_type(2))) u32 u32x2;
typedef __attribute__((ext_vector_type(4))) u32 u32x4;

#define DEV static __device__ __forceinline__
#define HW 16384

DEV u16 f2bf(float f) {
  u32 u = __float_as_uint(f);
  u = (u + 0x7fffu + ((u >> 16) & 1u)) >> 16;
  return (u16)u;
}
DEV float bf2f(u16 h) { return __uint_as_float(((u32)h) << 16); }

DEV u32 packsplit(float f) {
  u16 h = f2bf(f);
  u16 l = f2bf(f - bf2f(h));
  return (u32)h | ((u32)l << 16);
}
DEV void unpack8(const u32* w, short8& hi, short8& lo) {
  #pragma unroll
  for (int i = 0; i < 8; ++i) {
    hi[i] = (short)(u16)w[i];
    lo[i] = (short)(u16)(w[i] >> 16);
  }
}
DEV void mfma3(f32x4& acc, short8 ah, short8 al, short8 bh, short8 bl) {
  acc = __builtin_amdgcn_mfma_f32_16x16x32_bf16(ah, bh, acc, 0, 0, 0);
  acc = __builtin_amdgcn_mfma_f32_16x16x32_bf16(ah, bl, acc, 0, 0, 0);
  acc = __builtin_amdgcn_mfma_f32_16x16x32_bf16(al, bh, acc, 0, 0, 0);
}

// ---------------------------------------------------------------------------
// ksplit: f32 -> packed split-bf16 u32 (hi | lo<<16)
// ---------------------------------------------------------------------------
__global__ __launch_bounds__(256) void ksplit(const float* __restrict__ in,
                                              u32* __restrict__ out, int n) {
  int i = blockIdx.x * 256 + threadIdx.x;
  if (i < n) out[i] = packsplit(in[i]);
}

// ---------------------------------------------------------------------------
// gemm2: C[b][m][n] = A[(ab?b:0)][m][k] * B[b][k][n], M=K=192, f32 C,
// A pre-split packed u32; B f32 (BPACKED=0) or packed u32 (BPACKED=1).
// BM=192, BN=64, 8 waves (2m x 4n), 6 K-phases.
// ---------------------------------------------------------------------------
template<int ABATCH, int BPACKED>
__global__ __launch_bounds__(512, 4) void gemm2(const u32* __restrict__ Asp,
                                                const u32* __restrict__ B,
                                                float* __restrict__ C) {
  __shared__ u32 As[192 * 34];  // 26.1 KB
  __shared__ u32 Bs[64 * 34];   // 8.7 KB
  const int t = threadIdx.x, lane = t & 63, wid = t >> 6;
  const int b = blockIdx.z, n0 = blockIdx.x * 64;
  const u32* Ab = ABATCH ? (Asp + (size_t)b * 192 * 192) : Asp;
  const u32* Bb = B + (size_t)b * 192 * (size_t)HW;
  float* Cb = C + (size_t)b * 192 * (size_t)HW;
  const int wr = wid >> 2, wc = wid & 3;
  const int g = lane >> 4, r16 = lane & 15;
  const int b_n = (t & 15) * 4, b_k = t >> 4;
  f32x4 acc[6] = {};

  u32x4 Breg, Bnext;
  u32x4 Areg[3];
  Breg = *(const u32x4*)&Bb[(size_t)b_k * HW + n0 + b_n];
  #pragma unroll
  for (int i = 0; i < 3; ++i) {
    int vi = t + i * 512;
    Areg[i] = *(const u32x4*)&Ab[(size_t)(vi >> 3) * 192 + ((vi & 7) << 2)];
  }
  #pragma unroll 1
  for (int p = 0; p < 6; ++p) {
    #pragma unroll
    for (int j = 0; j < 4; ++j)
      Bs[(b_n + j) * 34 + b_k] = BPACKED ? Breg[j] : packsplit(__uint_as_float(Breg[j]));
    #pragma unroll
    for (int i = 0; i < 3; ++i) {
      int vi = t + i * 512;
      int row = vi >> 3, kc = (vi & 7) << 2;
      u32x2 v0 = {Areg[i][0], Areg[i][1]};
      u32x2 v1 = {Areg[i][2], Areg[i][3]};
      *(u32x2*)&As[row * 34 + kc] = v0;
      *(u32x2*)&As[row * 34 + kc + 2] = v1;
    }
    if (p < 5)
      Bnext = *(const u32x4*)&Bb[(size_t)((p + 1) * 32 + b_k) * HW + n0 + b_n];
    __syncthreads();
    if (p < 5) {
      #pragma unroll
      for (int i = 0; i < 3; ++i) {
        int vi = t + i * 512;
        Areg[i] = *(const u32x4*)&Ab[(size_t)(vi >> 3) * 192 + (p + 1) * 32 + ((vi & 7) << 2)];
      }
    }
    u32 bw[8];
    {
      const u32* bp = &Bs[(wc * 16 + r16) * 34 + g * 8];
      *(u32x2*)&bw[0] = *(const u32x2*)&bp[0];
      *(u32x2*)&bw[2] = *(const u32x2*)&bp[2];
      *(u32x2*)&bw[4] = *(const u32x2*)&bp[4];
      *(u32x2*)&bw[6] = *(const u32x2*)&bp[6];
    }
    short8 bh, bl; unpack8(bw, bh, bl);
    #pragma unroll
    for (int mf = 0; mf < 6; ++mf) {
      u32 aw[8];
      const u32* ap = &As[(wr * 96 + mf * 16 + r16) * 34 + g * 8];
      *(u32x2*)&aw[0] = *(const u32x2*)&ap[0];
      *(u32x2*)&aw[2] = *(const u32x2*)&ap[2];
      *(u32x2*)&aw[4] = *(const u32x2*)&ap[4];
      *(u32x2*)&aw[6] = *(const u32x2*)&ap[6];
      short8 ah, al; unpack8(aw, ah, al);
      acc[mf] = __builtin_amdgcn_mfma_f32_16x16x32_bf16(ah, bh, acc[mf], 0, 0, 0);
      acc[mf] = __builtin_amdgcn_mfma_f32_16x16x32_bf16(ah, bl, acc[mf], 0, 0, 0);
      acc[mf] = __builtin_amdgcn_mfma_f32_16x16x32_bf16(al, bh, acc[mf], 0, 0, 0);
    }
    __syncthreads();
    Breg = Bnext;
  }
  #pragma unroll
  for (int mf = 0; mf < 6; ++mf)
    #pragma unroll
    for (int rr = 0; rr < 4; ++rr)
      Cb[(size_t)(wr * 96 + mf * 16 + g * 4 + rr) * HW + n0 + wc * 16 + r16] =
          acc[mf][rr];
}

// ---------------------------------------------------------------------------
// K2: depthwise 3x3 (pad 1), f32 in, PACKED split-u32 out. 8 waves, one
// channel each; tile = 8 rows x 128 cols. Optional sum-of-squares partials.
// ---------------------------------------------------------------------------
template<int SSQ>
__global__ __launch_bounds__(512) void k2_dw(const float* __restrict__ Tin,
                                             const float* __restrict__ wdw, int wco,
                                             u32* __restrict__ O,
                                             float* __restrict__ ssq, int sspath) {
  const int rt = blockIdx.x, cg = blockIdx.y, b = blockIdx.z;
  const int t = threadIdx.x, lane = t & 63, w = t >> 6;
  __shared__ float In[8][10][132];
  for (int idx = t; idx < 10400; idx += 512) {
    int ch = idx / 1300, rem = idx % 1300;
    int r = rem / 130, ci = rem % 130;
    int gr = rt * 8 + r - 1, gc = ci - 1;
    float v = 0.f;
    if (gr >= 0 && gr < 128 && gc >= 0 && gc < 128)
      v = Tin[((size_t)b * 192 + cg * 8 + ch) * HW + gr * 128 + gc];
    In[ch][r][ci] = v;
  }
  float wv[9];
  #pragma unroll
  for (int j = 0; j < 9; ++j) wv[j] = wdw[(size_t)(wco + cg * 8 + w) * 9 + j];
  __syncthreads();
  float s = 0.f;
  u32* Op = O + ((size_t)b * 192 + cg * 8 + w) * HW + rt * 8 * 128 + 2 * lane;
  #pragma unroll
  for (int i = 0; i < 8; ++i) {
    float a0 = 0.f, a1 = 0.f;
    #pragma unroll
    for (int dr = 0; dr < 3; ++dr) {
      f32x2 u0 = *(const f32x2*)&In[w][i + dr][2 * lane];
      f32x2 u1 = *(const f32x2*)&In[w][i + dr][2 * lane + 2];
      a0 += wv[dr * 3] * u0[0] + wv[dr * 3 + 1] * u0[1] + wv[dr * 3 + 2] * u1[0];
      a1 += wv[dr * 3] * u0[1] + wv[dr * 3 + 1] * u1[0] + wv[dr * 3 + 2] * u1[1];
    }
    u32x2 o = {packsplit(a0), packsplit(a1)};
    *(u32x2*)&Op[(size_t)i * 128] = o;
    if (SSQ) s += a0 * a0 + a1 * a1;
  }
  if (SSQ) {
    #pragma unroll
    for (int off = 32; off; off >>= 1) s += __shfl_down(s, off);
    if (lane == 0) ssq[(((size_t)b * 2 + sspath) * 192 + cg * 8 + w) * 16 + rt] = s;
  }
}

// ---------------------------------------------------------------------------
// K3: Gram partials gp[bh][16][1024]: 4 waves each do a 256-px chunk from
// PACKED q/k, then in-block LDS reduction -> one 32x32 partial per block.
// ---------------------------------------------------------------------------
__global__ __launch_bounds__(256) void k3_gram(const u32* __restrict__ q,
                                               const u32* __restrict__ k,
                                               float* __restrict__ gp) {
  const int ck = blockIdx.x, bh = blockIdx.y;  // 16, 24
  const int b = bh / 6, h = bh % 6;
  const int t = threadIdx.x, lane = t & 63, wid = t >> 6;
  const int r16 = lane & 15, g = lane >> 4;
  const int chunk = ck * 4 + wid;  // 0..63
  const size_t rbase = ((size_t)b * 192 + h * 32 + r16) * HW;
  const u32* qp = q + rbase;
  const u32* kp = k + rbase;
  __shared__ float red[4][1024];
  f32x4 acc[2][2] = {};
  #pragma unroll 1
  for (int s = 0; s < 8; ++s) {
    int n = chunk * 256 + s * 32 + g * 8;
    u32 wq0[8], wq1[8], wk0[8], wk1[8];
    *(u32x4*)&wq0[0] = *(const u32x4*)&qp[n];
    *(u32x4*)&wq0[4] = *(const u32x4*)&qp[n + 4];
    *(u32x4*)&wq1[0] = *(const u32x4*)&qp[(size_t)16 * HW + n];
    *(u32x4*)&wq1[4] = *(const u32x4*)&qp[(size_t)16 * HW + n + 4];
    *(u32x4*)&wk0[0] = *(const u32x4*)&kp[n];
    *(u32x4*)&wk0[4] = *(const u32x4*)&kp[n + 4];
    *(u32x4*)&wk1[0] = *(const u32x4*)&kp[(size_t)16 * HW + n];
    *(u32x4*)&wk1[4] = *(const u32x4*)&kp[(size_t)16 * HW + n + 4];
    short8 a0h, a0l, a1h, a1l, b0h, b0l, b1h, b1l;
    unpack8(wq0, a0h, a0l);
    unpack8(wq1, a1h, a1l);
    unpack8(wk0, b0h, b0l);
    unpack8(wk1, b1h, b1l);
    mfma3(acc[0][0], a0h, a0l, b0h, b0l);
    mfma3(acc[0][1], a0h, a0l, b1h, b1l);
    mfma3(acc[1][0], a1h, a1l, b0h, b0l);
    mfma3(acc[1][1], a1h, a1l, b1h, b1l);
  }
  #pragma unroll
  for (int mf = 0; mf < 2; ++mf)
    #pragma unroll
    for (int nf = 0; nf < 2; ++nf)
      #pragma unroll
      for (int rr = 0; rr < 4; ++rr)
        red[wid][(mf * 16 + g * 4 + rr) * 32 + nf * 16 + r16] = acc[mf][nf][rr];
  __syncthreads();
  float* outp = gp + ((size_t)bh * 16 + ck) * 1024;
  #pragma unroll
  for (int e = t; e < 1024; e += 256)
    outp[e] = red[0][e] + red[1][e] + red[2][e] + red[3][e];
}

// ---------------------------------------------------------------------------
// K4: per (b,h): reduce 16 partials (vectorized, unrolled), normalize,
// temperature, 4x topk-softmax, combine, fold W_proj -> mcp packed u32
// ---------------------------------------------------------------------------
__global__ __launch_bounds__(256) void k4_comb(const float* __restrict__ gp,
                                               const float* __restrict__ ssq,
                                               const float* __restrict__ temp,
                                               const float* __restrict__ aw,
                                               const float* __restrict__ wproj,
                                               u32* __restrict__ mcp) {
  const int bh = blockIdx.x, b = bh / 6, h = bh % 6;
  const int t = threadIdx.x;
  __shared__ float Gs[1024];
  __shared__ float Acm[1024];
  __shared__ float nq[32], nk[32];
  {
    const float* p = gp + (size_t)bh * 16 * 1024 + 4 * t;
    f32x4 s = {};
    #pragma unroll
    for (int ch = 0; ch < 16; ++ch) {
      f32x4 v = *(const f32x4*)&p[(size_t)ch * 1024];
      s[0] += v[0]; s[1] += v[1]; s[2] += v[2]; s[3] += v[3];
    }
    *(f32x4*)&Gs[4 * t] = s;
  }
  if (t < 64) {
    int c = t & 31, pk = t >> 5;
    const float* sp = ssq + (((size_t)b * 2 + pk) * 192 + h * 32 + c) * 16;
    float s = 0.f;
    #pragma unroll
    for (int i = 0; i < 16; ++i) s += sp[i];
    float nr = fmaxf(sqrtf(s), 1e-12f);
    if (pk == 0) nq[c] = nr; else nk[c] = nr;
  }
  __syncthreads();
  const float T = temp[h];
  for (int e = t; e < 1024; e += 256) {
    int c = e >> 5, d = e & 31;
    Gs[e] = Gs[e] * T / (nq[c] * nk[d]);
  }
  __syncthreads();
  const float aw0 = aw[0], aw1 = aw[1], aw2 = aw[2], aw3 = aw[3];
  const int half = t >> 5, d = t & 31;
  for (int it = 0; it < 4; ++it) {
    const int c = it * 8 + half;
    const float v = Gs[c * 32 + d];
    int cnt = 0;
    #pragma unroll
    for (int dd = 0; dd < 32; ++dd) cnt += (Gs[c * 32 + dd] >= v) ? 1 : 0;
    float c0 = v;
    float c1 = (cnt >= 16) ? v : -3.0e38f;
    float c2 = (cnt >= 21) ? v : -3.0e38f;
    float c3 = (cnt >= 24) ? v : -3.0e38f;
    float c4 = (cnt >= 25) ? v : -3.0e38f;
    #pragma unroll
    for (int off = 16; off; off >>= 1) {
      c0 = fmaxf(c0, __shfl_xor(c0, off));
      c1 = fmaxf(c1, __shfl_xor(c1, off));
      c2 = fmaxf(c2, __shfl_xor(c2, off));
      c3 = fmaxf(c3, __shfl_xor(c3, off));
      c4 = fmaxf(c4, __shfl_xor(c4, off));
    }
    const float m = c0;
    const float ex = expf(v - m);
    float z1 = (v >= c1) ? ex : 0.f;
    float z2 = (v >= c2) ? ex : 0.f;
    float z3 = (v >= c3) ? ex : 0.f;
    float z4 = (v >= c4) ? ex : 0.f;
    #pragma unroll
    for (int off = 16; off; off >>= 1) {
      z1 += __shfl_xor(z1, off);
      z2 += __shfl_xor(z2, off);
      z3 += __shfl_xor(z3, off);
      z4 += __shfl_xor(z4, off);
    }
    float a = 0.f;
    a += (v >= c1) ? aw0 * ex / z1 : 0.f;
    a += (v >= c2) ? aw1 * ex / z2 : 0.f;
    a += (v >= c3) ? aw2 * ex / z3 : 0.f;
    a += (v >= c4) ? aw3 * ex / z4 : 0.f;
    Acm[c * 32 + d] = a;
  }
  __syncthreads();
  for (int idx = t; idx < 192 * 32; idx += 256) {
    int co = idx >> 5, dd = idx & 31;
    const float* wp = wproj + (size_t)co * 192 + h * 32;
    float s = 0.f;
    #pragma unroll
    for (int c = 0; c < 32; ++c) s += wp[c] * Acm[c * 32 + dd];
    mcp[((size_t)b * 192 + co) * 192 + h * 32 + dd] = packsplit(s);
  }
}

// ---------------------------------------------------------------------------
extern "C" void kernel_launch(void* const* d_in, const int* in_sizes, int n_in,
                              void* d_out, int out_size, void* d_ws, size_t ws_size,
                              hipStream_t stream) {
  const float* x     = (const float*)d_in[0];
  const float* ref   = (const float*)d_in[1];
  const float* wqkv  = (const float*)d_in[2];
  const float* wdw   = (const float*)d_in[3];
  const float* wproj = (const float*)d_in[4];
  const float* temp  = (const float*)d_in[5];
  const float* aw    = (const float*)d_in[6];
  float* out = (float*)d_out;
  char* ws = (char*)d_ws;

  const size_t S = (size_t)4 * 192 * HW * 4;  // 50331648 bytes
  float* tA  = (float*)(ws);
  float* tB  = (float*)(ws + S);
  u32*   qpk = (u32*)(ws + 2 * S);
  u32*   kpk = (u32*)(ws + 3 * S);
  float* gp  = (float*)(ws + 4 * S);                        // 1572864 B
  float* ssq = (float*)(ws + 4 * S + 1572864);              // 98304 B
  u32*   wsp = (u32*)(ws + 4 * S + 1572864 + 98304);        // 442368 B
  u32*   mcp = (u32*)(ws + 4 * S + 1572864 + 98304 + 442368); // 589824 B
  u32*   vpk = (u32*)tB;  // v packed output aliases tB (dead after k2 k)

  // pre-split w_qkv (576x192)
  ksplit<<<dim3(432), 256, 0, stream>>>(wqkv, wsp, 576 * 192);
  // q path
  gemm2<0, 0><<<dim3(256, 1, 4), 512, 0, stream>>>(wsp, (const u32*)x, tA);
  k2_dw<1><<<dim3(16, 24, 4), 512, 0, stream>>>(tA, wdw, 0, qpk, ssq, 0);
  // k path
  gemm2<0, 0><<<dim3(256, 1, 4), 512, 0, stream>>>(wsp + 192 * 192, (const u32*)ref, tB);
  k2_dw<1><<<dim3(16, 24, 4), 512, 0, stream>>>(tB, wdw, 192, kpk, ssq, 1);
  // Gram partials
  k3_gram<<<dim3(16, 24), 256, 0, stream>>>(qpk, kpk, gp);
  // v path (reuse tA for conv-out, pack into tB)
  gemm2<0, 0><<<dim3(256, 1, 4), 512, 0, stream>>>(wsp + 384 * 192, (const u32*)ref, tA);
  k2_dw<0><<<dim3(16, 24, 4), 512, 0, stream>>>(tA, wdw, 384, vpk, nullptr, 2);
  // combine + fold proj (writes packed mc)
  k4_comb<<<dim3(24), 256, 0, stream>>>(gp, ssq, temp, aw, wproj, mcp);
  // final batched GEMM (A batched packed, B packed)
  gemm2<1, 1><<<dim3(256, 1, 4), 512, 0, stream>>>(mcp, vpk, out);
}

// Round 5
// 233.044 us; speedup vs baseline: 1.4278x; 1.0335x over previous
//
#include <hip/hip_runtime.h>
#include <cstdint>
#include <cstddef>

typedef unsigned short u16;
typedef unsigned int u32;
typedef __attribute__((ext_vector_type(2))) float f32x2;
typedef __attribute__((ext_vector_type(4))) float f32x4;
typedef __attribute__((ext_vector_type(8))) short short8;
typedef __attribute__((ext_vector_type(2))) u32 u32x2;
typedef __attribute__((ext_vector_type(4))) u32 u32x4;

#define DEV static __device__ __forceinline__
#define HW 16384

DEV u16 f2bf(float f) {
  u32 u = __float_as_uint(f);
  u = (u + 0x7fffu + ((u >> 16) & 1u)) >> 16;
  return (u16)u;
}
DEV float bf2f(u16 h) { return __uint_as_float(((u32)h) << 16); }

DEV u32 packsplit(float f) {
  u16 h = f2bf(f);
  u16 l = f2bf(f - bf2f(h));
  return (u32)h | ((u32)l << 16);
}
DEV void unpack8(const u32* w, short8& hi, short8& lo) {
  #pragma unroll
  for (int i = 0; i < 8; ++i) {
    hi[i] = (short)(u16)w[i];
    lo[i] = (short)(u16)(w[i] >> 16);
  }
}
DEV void mfma3(f32x4& acc, short8 ah, short8 al, short8 bh, short8 bl) {
  acc = __builtin_amdgcn_mfma_f32_16x16x32_bf16(ah, bh, acc, 0, 0, 0);
  acc = __builtin_amdgcn_mfma_f32_16x16x32_bf16(ah, bl, acc, 0, 0, 0);
  acc = __builtin_amdgcn_mfma_f32_16x16x32_bf16(al, bh, acc, 0, 0, 0);
}

// ---------------------------------------------------------------------------
// ksplit: f32 -> packed split-bf16 u32 (hi | lo<<16)
// ---------------------------------------------------------------------------
__global__ __launch_bounds__(256) void ksplit(const float* __restrict__ in,
                                              u32* __restrict__ out, int n) {
  int i = blockIdx.x * 256 + threadIdx.x;
  if (i < n) out[i] = packsplit(in[i]);
}

// ---------------------------------------------------------------------------
// gemm2: C[b][m][n] = A[(ab?b:0)][m][k] * B[b][k][n], K=192, M=MFRAG*32,
// f32 C; A pre-split packed u32; B f32 (BPACKED=0) or packed u32 (BPACKED=1).
// BM=M, BN=64, 8 waves (2m x 4n), 6 K-phases.
// ---------------------------------------------------------------------------
template<int ABATCH, int BPACKED, int MFRAG>
__global__ __launch_bounds__(512, 4) void gemm2(const u32* __restrict__ Asp,
                                                const u32* __restrict__ B,
                                                float* __restrict__ C) {
  constexpr int BM = MFRAG * 32;
  __shared__ u32 As[BM * 34];
  __shared__ u32 Bs[64 * 34];
  const int t = threadIdx.x, lane = t & 63, wid = t >> 6;
  const int b = blockIdx.z, n0 = blockIdx.x * 64;
  const u32* Ab = ABATCH ? (Asp + (size_t)b * 192 * 192) : Asp;
  const u32* Bb = B + (size_t)b * 192 * (size_t)HW;
  float* Cb = C + (size_t)b * BM * (size_t)HW;
  const int wr = wid >> 2, wc = wid & 3;
  const int g = lane >> 4, r16 = lane & 15;
  const int b_n = (t & 15) * 4, b_k = t >> 4;
  f32x4 acc[MFRAG] = {};

  u32x4 Breg, Bnext;
  u32x4 Areg[MFRAG / 2];
  Breg = *(const u32x4*)&Bb[(size_t)b_k * HW + n0 + b_n];
  #pragma unroll
  for (int i = 0; i < MFRAG / 2; ++i) {
    int vi = t + i * 512;
    Areg[i] = *(const u32x4*)&Ab[(size_t)(vi >> 3) * 192 + ((vi & 7) << 2)];
  }
  #pragma unroll 1
  for (int p = 0; p < 6; ++p) {
    #pragma unroll
    for (int j = 0; j < 4; ++j)
      Bs[(b_n + j) * 34 + b_k] = BPACKED ? Breg[j] : packsplit(__uint_as_float(Breg[j]));
    #pragma unroll
    for (int i = 0; i < MFRAG / 2; ++i) {
      int vi = t + i * 512;
      int row = vi >> 3, kc = (vi & 7) << 2;
      u32x2 v0 = {Areg[i][0], Areg[i][1]};
      u32x2 v1 = {Areg[i][2], Areg[i][3]};
      *(u32x2*)&As[row * 34 + kc] = v0;
      *(u32x2*)&As[row * 34 + kc + 2] = v1;
    }
    if (p < 5)
      Bnext = *(const u32x4*)&Bb[(size_t)((p + 1) * 32 + b_k) * HW + n0 + b_n];
    __syncthreads();
    if (p < 5) {
      #pragma unroll
      for (int i = 0; i < MFRAG / 2; ++i) {
        int vi = t + i * 512;
        Areg[i] = *(const u32x4*)&Ab[(size_t)(vi >> 3) * 192 + (p + 1) * 32 + ((vi & 7) << 2)];
      }
    }
    u32 bw[8];
    {
      const u32* bp = &Bs[(wc * 16 + r16) * 34 + g * 8];
      *(u32x2*)&bw[0] = *(const u32x2*)&bp[0];
      *(u32x2*)&bw[2] = *(const u32x2*)&bp[2];
      *(u32x2*)&bw[4] = *(const u32x2*)&bp[4];
      *(u32x2*)&bw[6] = *(const u32x2*)&bp[6];
    }
    short8 bh, bl; unpack8(bw, bh, bl);
    #pragma unroll
    for (int mf = 0; mf < MFRAG; ++mf) {
      u32 aw[8];
      const u32* ap = &As[(wr * (MFRAG * 16) + mf * 16 + r16) * 34 + g * 8];
      *(u32x2*)&aw[0] = *(const u32x2*)&ap[0];
      *(u32x2*)&aw[2] = *(const u32x2*)&ap[2];
      *(u32x2*)&aw[4] = *(const u32x2*)&ap[4];
      *(u32x2*)&aw[6] = *(const u32x2*)&ap[6];
      short8 ah, al; unpack8(aw, ah, al);
      acc[mf] = __builtin_amdgcn_mfma_f32_16x16x32_bf16(ah, bh, acc[mf], 0, 0, 0);
      acc[mf] = __builtin_amdgcn_mfma_f32_16x16x32_bf16(ah, bl, acc[mf], 0, 0, 0);
      acc[mf] = __builtin_amdgcn_mfma_f32_16x16x32_bf16(al, bh, acc[mf], 0, 0, 0);
    }
    __syncthreads();
    Breg = Bnext;
  }
  #pragma unroll
  for (int mf = 0; mf < MFRAG; ++mf)
    #pragma unroll
    for (int rr = 0; rr < 4; ++rr)
      Cb[(size_t)(wr * (MFRAG * 16) + mf * 16 + g * 4 + rr) * HW + n0 + wc * 16 + r16] =
          acc[mf][rr];
}

// ---------------------------------------------------------------------------
// K2: depthwise 3x3 (pad 1), f32 in (batch stride cstIn*HW), PACKED u32 out
// (batch stride 192*HW). 8 waves, one channel each; tile 8 rows x 128 cols.
// ---------------------------------------------------------------------------
template<int SSQ>
__global__ __launch_bounds__(512) void k2_dw(const float* __restrict__ Tin, int cstIn,
                                             const float* __restrict__ wdw, int wco,
                                             u32* __restrict__ O,
                                             float* __restrict__ ssq, int sspath) {
  const int rt = blockIdx.x, cg = blockIdx.y, b = blockIdx.z;
  const int t = threadIdx.x, lane = t & 63, w = t >> 6;
  __shared__ float In[8][10][132];
  for (int idx = t; idx < 10400; idx += 512) {
    int ch = idx / 1300, rem = idx % 1300;
    int r = rem / 130, ci = rem % 130;
    int gr = rt * 8 + r - 1, gc = ci - 1;
    float v = 0.f;
    if (gr >= 0 && gr < 128 && gc >= 0 && gc < 128)
      v = Tin[((size_t)b * cstIn + cg * 8 + ch) * HW + gr * 128 + gc];
    In[ch][r][ci] = v;
  }
  float wv[9];
  #pragma unroll
  for (int j = 0; j < 9; ++j) wv[j] = wdw[(size_t)(wco + cg * 8 + w) * 9 + j];
  __syncthreads();
  float s = 0.f;
  u32* Op = O + ((size_t)b * 192 + cg * 8 + w) * HW + rt * 8 * 128 + 2 * lane;
  #pragma unroll
  for (int i = 0; i < 8; ++i) {
    float a0 = 0.f, a1 = 0.f;
    #pragma unroll
    for (int dr = 0; dr < 3; ++dr) {
      f32x2 u0 = *(const f32x2*)&In[w][i + dr][2 * lane];
      f32x2 u1 = *(const f32x2*)&In[w][i + dr][2 * lane + 2];
      a0 += wv[dr * 3] * u0[0] + wv[dr * 3 + 1] * u0[1] + wv[dr * 3 + 2] * u1[0];
      a1 += wv[dr * 3] * u0[1] + wv[dr * 3 + 1] * u1[0] + wv[dr * 3 + 2] * u1[1];
    }
    u32x2 o = {packsplit(a0), packsplit(a1)};
    *(u32x2*)&Op[(size_t)i * 128] = o;
    if (SSQ) s += a0 * a0 + a1 * a1;
  }
  if (SSQ) {
    #pragma unroll
    for (int off = 32; off; off >>= 1) s += __shfl_down(s, off);
    if (lane == 0) ssq[(((size_t)b * 2 + sspath) * 192 + cg * 8 + w) * 16 + rt] = s;
  }
}

// ---------------------------------------------------------------------------
// K3: Gram partials gp[bh][16][1024]: 4 waves each do a 256-px chunk from
// PACKED q/k, then in-block LDS reduction -> one 32x32 partial per block.
// ---------------------------------------------------------------------------
__global__ __launch_bounds__(256) void k3_gram(const u32* __restrict__ q,
                                               const u32* __restrict__ k,
                                               float* __restrict__ gp) {
  const int ck = blockIdx.x, bh = blockIdx.y;  // 16, 24
  const int b = bh / 6, h = bh % 6;
  const int t = threadIdx.x, lane = t & 63, wid = t >> 6;
  const int r16 = lane & 15, g = lane >> 4;
  const int chunk = ck * 4 + wid;  // 0..63
  const size_t rbase = ((size_t)b * 192 + h * 32 + r16) * HW;
  const u32* qp = q + rbase;
  const u32* kp = k + rbase;
  __shared__ float red[4][1024];
  f32x4 acc[2][2] = {};
  #pragma unroll 1
  for (int s = 0; s < 8; ++s) {
    int n = chunk * 256 + s * 32 + g * 8;
    u32 wq0[8], wq1[8], wk0[8], wk1[8];
    *(u32x4*)&wq0[0] = *(const u32x4*)&qp[n];
    *(u32x4*)&wq0[4] = *(const u32x4*)&qp[n + 4];
    *(u32x4*)&wq1[0] = *(const u32x4*)&qp[(size_t)16 * HW + n];
    *(u32x4*)&wq1[4] = *(const u32x4*)&qp[(size_t)16 * HW + n + 4];
    *(u32x4*)&wk0[0] = *(const u32x4*)&kp[n];
    *(u32x4*)&wk0[4] = *(const u32x4*)&kp[n + 4];
    *(u32x4*)&wk1[0] = *(const u32x4*)&kp[(size_t)16 * HW + n];
    *(u32x4*)&wk1[4] = *(const u32x4*)&kp[(size_t)16 * HW + n + 4];
    short8 a0h, a0l, a1h, a1l, b0h, b0l, b1h, b1l;
    unpack8(wq0, a0h, a0l);
    unpack8(wq1, a1h, a1l);
    unpack8(wk0, b0h, b0l);
    unpack8(wk1, b1h, b1l);
    mfma3(acc[0][0], a0h, a0l, b0h, b0l);
    mfma3(acc[0][1], a0h, a0l, b1h, b1l);
    mfma3(acc[1][0], a1h, a1l, b0h, b0l);
    mfma3(acc[1][1], a1h, a1l, b1h, b1l);
  }
  #pragma unroll
  for (int mf = 0; mf < 2; ++mf)
    #pragma unroll
    for (int nf = 0; nf < 2; ++nf)
      #pragma unroll
      for (int rr = 0; rr < 4; ++rr)
        red[wid][(mf * 16 + g * 4 + rr) * 32 + nf * 16 + r16] = acc[mf][nf][rr];
  __syncthreads();
  float* outp = gp + ((size_t)bh * 16 + ck) * 1024;
  #pragma unroll
  for (int e = t; e < 1024; e += 256)
    outp[e] = red[0][e] + red[1][e] + red[2][e] + red[3][e];
}

// ---------------------------------------------------------------------------
// K4: per (b,h): reduce 16 partials, normalize, temperature, 4x topk-softmax,
// combine, fold W_proj (LDS-cached) -> mcp packed u32.  512 threads.
// ---------------------------------------------------------------------------
__global__ __launch_bounds__(512) void k4_comb(const float* __restrict__ gp,
                                               const float* __restrict__ ssq,
                                               const float* __restrict__ temp,
                                               const float* __restrict__ aw,
                                               const float* __restrict__ wproj,
                                               u32* __restrict__ mcp) {
  const int bh = blockIdx.x, b = bh / 6, h = bh % 6;
  const int t = threadIdx.x;
  __shared__ float Gs[1024];
  __shared__ float Acm[1024];
  __shared__ float Wp[192 * 32];
  __shared__ float nq[32], nk[32];
  // preload wproj slice [192][h*32..h*32+32) -> Wp (coalesced f32x4)
  #pragma unroll
  for (int i = 0; i < 3; ++i) {
    int idx = t + i * 512;          // f32x4 units, 1536 total
    int row = idx >> 3, c4 = (idx & 7) << 2;
    *(f32x4*)&Wp[row * 32 + c4] = *(const f32x4*)&wproj[(size_t)row * 192 + h * 32 + c4];
  }
  // gp reduce: 2 elems/thread as f32x2, 16 independent loads
  {
    const float* p = gp + (size_t)bh * 16 * 1024 + 2 * t;
    f32x2 s = {};
    #pragma unroll
    for (int ch = 0; ch < 16; ++ch) {
      f32x2 v = *(const f32x2*)&p[(size_t)ch * 1024];
      s[0] += v[0]; s[1] += v[1];
    }
    *(f32x2*)&Gs[2 * t] = s;
  }
  if (t < 64) {
    int c = t & 31, pk = t >> 5;
    const float* sp = ssq + (((size_t)b * 2 + pk) * 192 + h * 32 + c) * 16;
    f32x4 s4 = {};
    #pragma unroll
    for (int i = 0; i < 4; ++i) {
      f32x4 v = *(const f32x4*)&sp[4 * i];
      s4[0] += v[0]; s4[1] += v[1]; s4[2] += v[2]; s4[3] += v[3];
    }
    float nr = fmaxf(sqrtf(s4[0] + s4[1] + s4[2] + s4[3]), 1e-12f);
    if (pk == 0) nq[c] = nr; else nk[c] = nr;
  }
  __syncthreads();
  const float T = temp[h];
  {
    int c = (2 * t) >> 5;
    f32x2 v = *(const f32x2*)&Gs[2 * t];
    float inq = T / nq[c];
    v[0] = v[0] * inq / nk[(2 * t) & 31];
    v[1] = v[1] * inq / nk[(2 * t + 1) & 31];
    __syncthreads();
    *(f32x2*)&Gs[2 * t] = v;
  }
  __syncthreads();
  const float aw0 = aw[0], aw1 = aw[1], aw2 = aw[2], aw3 = aw[3];
  const int half = t >> 5, d = t & 31;
  #pragma unroll
  for (int it = 0; it < 2; ++it) {
    const int c = it * 16 + half;
    const float v = Gs[c * 32 + d];
    int cnt = 0;
    #pragma unroll
    for (int dd = 0; dd < 32; ++dd) cnt += (Gs[c * 32 + dd] >= v) ? 1 : 0;
    float c0 = v;
    float c1 = (cnt >= 16) ? v : -3.0e38f;
    float c2 = (cnt >= 21) ? v : -3.0e38f;
    float c3 = (cnt >= 24) ? v : -3.0e38f;
    float c4 = (cnt >= 25) ? v : -3.0e38f;
    #pragma unroll
    for (int off = 16; off; off >>= 1) {
      c0 = fmaxf(c0, __shfl_xor(c0, off));
      c1 = fmaxf(c1, __shfl_xor(c1, off));
      c2 = fmaxf(c2, __shfl_xor(c2, off));
      c3 = fmaxf(c3, __shfl_xor(c3, off));
      c4 = fmaxf(c4, __shfl_xor(c4, off));
    }
    const float m = c0;
    const float ex = expf(v - m);
    float z1 = (v >= c1) ? ex : 0.f;
    float z2 = (v >= c2) ? ex : 0.f;
    float z3 = (v >= c3) ? ex : 0.f;
    float z4 = (v >= c4) ? ex : 0.f;
    #pragma unroll
    for (int off = 16; off; off >>= 1) {
      z1 += __shfl_xor(z1, off);
      z2 += __shfl_xor(z2, off);
      z3 += __shfl_xor(z3, off);
      z4 += __shfl_xor(z4, off);
    }
    float a = 0.f;
    a += (v >= c1) ? aw0 * ex / z1 : 0.f;
    a += (v >= c2) ? aw1 * ex / z2 : 0.f;
    a += (v >= c3) ? aw2 * ex / z3 : 0.f;
    a += (v >= c4) ? aw3 * ex / z4 : 0.f;
    Acm[c * 32 + d] = a;
  }
  __syncthreads();
  #pragma unroll
  for (int i = 0; i < 12; ++i) {
    int idx = t + i * 512;
    int co = idx >> 5, dd = idx & 31;
    float s = 0.f;
    #pragma unroll
    for (int c = 0; c < 32; ++c) s += Wp[co * 32 + c] * Acm[c * 32 + dd];
    mcp[((size_t)b * 192 + co) * 192 + h * 32 + dd] = packsplit(s);
  }
}

// ---------------------------------------------------------------------------
extern "C" void kernel_launch(void* const* d_in, const int* in_sizes, int n_in,
                              void* d_out, int out_size, void* d_ws, size_t ws_size,
                              hipStream_t stream) {
  const float* x     = (const float*)d_in[0];
  const float* ref   = (const float*)d_in[1];
  const float* wqkv  = (const float*)d_in[2];
  const float* wdw   = (const float*)d_in[3];
  const float* wproj = (const float*)d_in[4];
  const float* temp  = (const float*)d_in[5];
  const float* aw    = (const float*)d_in[6];
  float* out = (float*)d_out;
  char* ws = (char*)d_ws;

  const size_t S = (size_t)4 * 192 * HW * 4;  // 50331648 bytes
  float* tA  = (float*)(ws);                  // q conv-out; later kpk
  float* tKV = (float*)(ws + S);              // k+v conv-out (2S); later vpk
  u32*   qpk = (u32*)(ws + 3 * S);            // packed q; later vpk
  float* gp  = (float*)(ws + 4 * S);                        // 1572864 B
  float* ssq = (float*)(ws + 4 * S + 1572864);              // 98304 B
  u32*   wsp = (u32*)(ws + 4 * S + 1572864 + 98304);        // 442368 B
  u32*   mcp = (u32*)(ws + 4 * S + 1572864 + 98304 + 442368); // 589824 B
  u32*   kpk = (u32*)tA;
  u32*   vpk = qpk;

  // pre-split w_qkv (576x192)
  ksplit<<<dim3(432), 256, 0, stream>>>(wqkv, wsp, 576 * 192);
  // q path
  gemm2<0, 0, 6><<<dim3(256, 1, 4), 512, 0, stream>>>(wsp, (const u32*)x, tA);
  k2_dw<1><<<dim3(16, 24, 4), 512, 0, stream>>>(tA, 192, wdw, 0, qpk, ssq, 0);
  // k+v merged conv1x1 (M=384, ref read once)
  gemm2<0, 0, 12><<<dim3(256, 1, 4), 512, 0, stream>>>(wsp + 192 * 192, (const u32*)ref, tKV);
  // k dwconv (rows 0..191 of tKV) -> kpk (= old tA, dead)
  k2_dw<1><<<dim3(16, 24, 4), 512, 0, stream>>>(tKV, 384, wdw, 192, kpk, ssq, 1);
  // Gram partials (before k2v so qpk can be recycled)
  k3_gram<<<dim3(16, 24), 256, 0, stream>>>(qpk, kpk, gp);
  // v dwconv (rows 192..383 of tKV) -> vpk (= qpk, dead after k3)
  k2_dw<0><<<dim3(16, 24, 4), 512, 0, stream>>>(tKV + (size_t)192 * HW, 384, wdw, 384, vpk, nullptr, 2);
  // combine + fold proj (writes packed mc)
  k4_comb<<<dim3(24), 512, 0, stream>>>(gp, ssq, temp, aw, wproj, mcp);
  // final batched GEMM (A batched packed, B packed)
  gemm2<1, 1, 6><<<dim3(256, 1, 4), 512, 0, stream>>>(mcp, vpk, out);
}